// Round 1
// 259.978 us; speedup vs baseline: 1.6209x; 1.6209x over previous
//
#include <hip/hip_runtime.h>
#include <stdint.h>

#define N_ROWS 32768
#define K_CODES 8192
#define D_DIM 256
#define STEP_BYTES 36864   // 32 KiB bf16 codes + 4 KiB c2 hi/lo slice
#define NBUF 4

typedef __attribute__((ext_vector_type(8))) short short8;
typedef __attribute__((ext_vector_type(4))) float f32x4;
typedef __attribute__((ext_vector_type(2))) float f32x2;

__device__ __forceinline__ unsigned short f2bf_rne(float f) {
  union { float f; unsigned u; } v; v.f = f;
  unsigned r = v.u + 0x7fffu + ((v.u >> 16) & 1u);
  return (unsigned short)(r >> 16);
}
__device__ __forceinline__ float bf2f(unsigned short h) {
  union { unsigned u; float f; } v; v.u = ((unsigned)h) << 16;
  return v.f;
}

// ---------------------------------------------------------------------------
// Prep: codebook fp32 -> bf16 (RNE), XOR-swizzled within each 512B row.
// NEW: each 64-code step block carries a 4 KiB "channel 8" slice holding
// -|e|^2/2 as a bf16 hi+lo pair at k-elems 0,1 (rest zero), swizzled the same
// way the compute-side ds_read expects. This removes the per-iter global ck2
// load from the argmin pipeline (it was the only compiler-guarded VMEM value
// inside the counted-vmcnt loop). Zeroes counts.
// ---------------------------------------------------------------------------
__global__ __launch_bounds__(256) void eprep_kernel(
    const float* __restrict__ cb, unsigned short* __restrict__ ehw,
    int* __restrict__ counts) {
  int w = threadIdx.x >> 6, lane = threadIdx.x & 63;
  int k = blockIdx.x * 4 + w;
  int gid = blockIdx.x * 256 + threadIdx.x;
  if (gid < K_CODES) counts[gid] = 0;
  const float4* src = (const float4*)(cb + (size_t)k * D_DIM);
  float4 v = src[lane];
  float vv[4] = {v.x, v.y, v.z, v.w};
  unsigned short h[4];
  float s = 0.f;
#pragma unroll
  for (int j = 0; j < 4; ++j) {
    float f = vv[j];
    s += f * f;
    h[j] = f2bf_rne(f);
  }
  char* stepb = (char*)ehw + (size_t)(k >> 6) * STEP_BYTES;
  int cl = k & 63;
  int off = (8 * lane) ^ ((k & 7) << 4);  // swizzle flips bits 4-6 only
  *(ushort4*)(stepb + cl * 512 + off) = make_ushort4(h[0], h[1], h[2], h[3]);
#pragma unroll
  for (int m = 1; m < 64; m <<= 1) s += __shfl_xor(s, m);
  // -|e|^2/2 as bf16 hi+lo (error ~2^-12): consumed by the extra MFMA channel
  float t = -0.5f * s;
  unsigned short hi = f2bf_rne(t);
  unsigned short lo = f2bf_rne(t - bf2f(hi));
  if (lane < 4) {
    short8 c = {0, 0, 0, 0, 0, 0, 0, 0};
    if (lane == 0) { c[0] = (short)hi; c[1] = (short)lo; }
    int o2 = 32768 + cl * 64 + ((lane * 16) ^ ((cl & 3) << 4));
    *(short8*)(stepb + o2) = c;
  }
}

// ---------------------------------------------------------------------------
// Argmin with T3+T4 counted-vmcnt pipeline (depth 3, 4 LDS buffers), now with:
//  (a) the 1.07 GiB encodings zero-fill interleaved as nt dwordx2 stores
//      (8 stores/lane/iter = 1 enc row/block/iter), hidden under the K loop;
//  (b) -|e|^2/2 delivered via a 9th MFMA channel from the staged tile, so the
//      loop's VMEM stream is exactly {6 load_lds + 8 stores}/iter and the
//      vmcnt counting is exact (wait = 8S + 2*(6L+8S) = 36, uniform).
//  (c) the one-hot 1.0 scatter folded into the epilogue (vmcnt(0)+barrier
//      orders it after all 8 waves' zero stores at L2).
// 256 blocks x 128 rows; 8 waves = 2 row-groups x 4 code-groups.
// ---------------------------------------------------------------------------
__global__ __launch_bounds__(512, 1) void argmin_kernel(
    const float* __restrict__ x, const float* __restrict__ cb,
    const unsigned short* __restrict__ ehw,
    float* __restrict__ quant, int* __restrict__ counts,
    float* __restrict__ ssep, float* __restrict__ enc) {
  __shared__ __align__(16) char s_tiles[NBUF * STEP_BYTES];  // 144 KiB
  __shared__ float s_x2[128];
  __shared__ float s_red[128];
  // epilogue-only arrays aliased onto s_tiles (buf0 dead after COMPUTE(124)):
  float (*s_mn)[128] = (float (*)[128])(s_tiles);          // 2 KiB
  int (*s_mi)[128] = (int (*)[128])(s_tiles + 2048);       // 2 KiB

  const int tid = threadIdx.x;
  const int abid = blockIdx.x;
  const int ww = tid >> 6;
  const int lane = tid & 63;
  const int l15 = lane & 15;
  const int kg = lane >> 4;
  const int rg = ww >> 2;             // row group (0..1), 64 rows each
  const int cg = ww & 3;              // code group (0..3), 16 codes each
  const int row0 = abid * 128;

  auto STAGE = [&](int i, int b) {
    const char* g0 = (const char*)ehw + (size_t)i * STEP_BYTES + ww * 4096 + lane * 16;
    char* l0 = s_tiles + b * STEP_BYTES + ww * 4096;  // wave-uniform base
#pragma unroll
    for (int j = 0; j < 4; ++j) {
      __builtin_amdgcn_global_load_lds(
          (const __attribute__((address_space(1))) unsigned int*)(g0 + j * 1024),
          (__attribute__((address_space(3))) unsigned int*)(l0 + j * 1024), 16, 0, 0);
    }
    const char* g1 = (const char*)ehw + (size_t)i * STEP_BYTES + 32768 + ww * 512 + lane * 4;
    char* l1 = s_tiles + b * STEP_BYTES + 32768 + ww * 512;
#pragma unroll
    for (int j = 0; j < 2; ++j) {
      __builtin_amdgcn_global_load_lds(
          (const __attribute__((address_space(1))) unsigned int*)(g1 + j * 256),
          (__attribute__((address_space(3))) unsigned int*)(l1 + j * 256), 4, 0, 0);
    }
  };

  // zero-fill of this block's 128 encodings rows: 1 row (32 KiB) per unit,
  // 8 waves x 8 x dwordx2 (512 B each, contiguous 1 KiB per wave-store).
  // dwordx2 because enc is only 8-mod-16 aligned. nt: don't thrash the eh L2.
  const f32x2 z2 = {0.f, 0.f};
  char* zp = (char*)enc + (size_t)row0 * 32768 + ww * 4096 + lane * 8;
  auto ZST = [&](const char* p) {
    asm volatile(
        "global_store_dwordx2 %0, %1, off nt\n\t"
        "global_store_dwordx2 %0, %1, off offset:512 nt\n\t"
        "global_store_dwordx2 %0, %1, off offset:1024 nt\n\t"
        "global_store_dwordx2 %0, %1, off offset:1536 nt\n\t"
        "global_store_dwordx2 %0, %1, off offset:2048 nt\n\t"
        "global_store_dwordx2 %0, %1, off offset:2560 nt\n\t"
        "global_store_dwordx2 %0, %1, off offset:3072 nt\n\t"
        "global_store_dwordx2 %0, %1, off offset:3584 nt"
        :: "v"(p), "v"(z2) : "memory");
  };

  // prologue: pipeline 3 deep + 3 zero units so the vmcnt stream is uniform:
  // before COMPUTE(0), ops younger than STAGE(0) = 12L + 24S... = 36 exactly.
  STAGE(0, 0); STAGE(1, 1); STAGE(2, 2);
  ZST(zp); ZST(zp + 32768); ZST(zp + 65536);

  // load & convert A fragments: 64 rows/wave (4 subtiles of 16), bf16 hi only
  short8 a_h[4][8];
  float x2acc[4];
#pragma unroll
  for (int s = 0; s < 4; ++s) {
    const float* rp = x + (size_t)(row0 + rg * 64 + s * 16 + l15) * D_DIM + kg * 8;
    float s2 = 0.f;
#pragma unroll
    for (int ch = 0; ch < 8; ++ch) {
      const float4* p = (const float4*)(rp + ch * 32);
      float4 v0 = p[0], v1 = p[1];
      float f[8] = {v0.x, v0.y, v0.z, v0.w, v1.x, v1.y, v1.z, v1.w};
#pragma unroll
      for (int j = 0; j < 8; ++j) {
        s2 += f[j] * f[j];
        a_h[s][ch][j] = (short)f2bf_rne(f[j]);
      }
    }
    x2acc[s] = s2;
  }
#pragma unroll
  for (int s = 0; s < 4; ++s) {
    x2acc[s] += __shfl_xor(x2acc[s], 16);
    x2acc[s] += __shfl_xor(x2acc[s], 32);
  }
  if (cg == 0 && lane < 16) {  // kg==0 lanes
#pragma unroll
    for (int s = 0; s < 4; ++s) s_x2[rg * 64 + s * 16 + l15] = x2acc[s];
  }

  // A fragment for the c2 channel: 1.0 at k=0 (kg==0 lanes only)
  short8 a1 = {0, 0, 0, 0, 0, 0, 0, 0};
  if (kg == 0) a1[0] = (short)0x3F80;

  float mn[16];
  int mi[16];
#pragma unroll
  for (int s = 0; s < 16; ++s) { mn[s] = 3.4e38f; mi[s] = 0x7fffffff; }

  const int c_local = cg * 16 + l15;     // lane's code within the 64-code step
  const int rb = c_local * 512;
  const int xm = (l15 & 7) << 4;         // (code&7)<<4
  const int c2off = 32768 + c_local * 64 + ((kg * 16) ^ ((l15 & 3) << 4));

  auto COMPUTE = [&](int t) {
    const char* bh = s_tiles + (t & 3) * STEP_BYTES;
    const int code = t * 64 + c_local;
    f32x4 acc[4];
#pragma unroll
    for (int s = 0; s < 4; ++s) acc[s] = (f32x4){0.f, 0.f, 0.f, 0.f};
#pragma unroll
    for (int ch = 0; ch < 8; ++ch) {
      const int off = rb + ((ch * 64 + kg * 16) ^ xm);
      short8 vh = *(const short8*)(bh + off);
      acc[0] = __builtin_amdgcn_mfma_f32_16x16x32_bf16(a_h[0][ch], vh, acc[0], 0, 0, 0);
      acc[1] = __builtin_amdgcn_mfma_f32_16x16x32_bf16(a_h[1][ch], vh, acc[1], 0, 0, 0);
      acc[2] = __builtin_amdgcn_mfma_f32_16x16x32_bf16(a_h[2][ch], vh, acc[2], 0, 0, 0);
      acc[3] = __builtin_amdgcn_mfma_f32_16x16x32_bf16(a_h[3][ch], vh, acc[3], 0, 0, 0);
    }
    // channel 8: acc += 1.0 * (-|e|^2/2)  (bf16 hi+lo pair at k=0,1)
    short8 vh8 = *(const short8*)(bh + c2off);
    acc[0] = __builtin_amdgcn_mfma_f32_16x16x32_bf16(a1, vh8, acc[0], 0, 0, 0);
    acc[1] = __builtin_amdgcn_mfma_f32_16x16x32_bf16(a1, vh8, acc[1], 0, 0, 0);
    acc[2] = __builtin_amdgcn_mfma_f32_16x16x32_bf16(a1, vh8, acc[2], 0, 0, 0);
    acc[3] = __builtin_amdgcn_mfma_f32_16x16x32_bf16(a1, vh8, acc[3], 0, 0, 0);
#pragma unroll
    for (int s = 0; s < 4; ++s) {
#pragma unroll
      for (int r = 0; r < 4; ++r) {
        float d = -2.f * acc[s][r];      // = |e|^2 - 2 x.e
        if (d < mn[s * 4 + r]) { mn[s * 4 + r] = d; mi[s * 4 + r] = code; }
      }
    }
  };

  char* zr = zp + 3 * 32768;
#pragma unroll 1
  for (int t = 0; t < 125; ++t) {
    // ops younger than STAGE(t): 8S + (6L+8S)*2 = 36 -> stage t complete
    asm volatile("s_waitcnt vmcnt(36)" ::: "memory");
    __builtin_amdgcn_s_barrier();
    __builtin_amdgcn_sched_barrier(0);
    COMPUTE(t);
    STAGE(t + 3, (t + 3) & 3);  // overwrites buf (t-1)&3: readers done at barrier
    ZST(zr);                    // zero enc row row0 + t + 3
    zr += 32768;
  }
  asm volatile("s_waitcnt vmcnt(36)" ::: "memory");
  __builtin_amdgcn_s_barrier();
  __builtin_amdgcn_sched_barrier(0);
  COMPUTE(125);
  asm volatile("s_waitcnt vmcnt(22)" ::: "memory");
  __builtin_amdgcn_s_barrier();
  __builtin_amdgcn_sched_barrier(0);
  COMPUTE(126);
  asm volatile("s_waitcnt vmcnt(8)" ::: "memory");
  __builtin_amdgcn_s_barrier();
  __builtin_amdgcn_sched_barrier(0);
  COMPUTE(127);

  // reduce across the 16 lanes (l15) holding different codes of the same rows
#pragma unroll
  for (int m = 1; m < 16; m <<= 1) {
#pragma unroll
    for (int s = 0; s < 16; ++s) {
      float om = __shfl_xor(mn[s], m);
      int oi = __shfl_xor(mi[s], m);
      if (om < mn[s] || (om == mn[s] && oi < mi[s])) { mn[s] = om; mi[s] = oi; }
    }
  }
  if (l15 == 0) {
#pragma unroll
    for (int s = 0; s < 4; ++s)
#pragma unroll
      for (int r = 0; r < 4; ++r)
        { int lr = rg * 64 + s * 16 + kg * 4 + r;
          s_mn[cg][lr] = mn[s * 4 + r]; s_mi[cg][lr] = mi[s * 4 + r]; }
  }
  // drain this wave's zero stores; barrier => all waves' zeros are at L2
  // before any 1.0 one-hot store below.
  asm volatile("s_waitcnt vmcnt(0)" ::: "memory");
  __syncthreads();

  // merge 4 code-groups; one-hot 1.0 scatter; histogram; SSE partial
  if (tid < 128) {
    float bm = s_mn[0][tid]; int best = s_mi[0][tid];
#pragma unroll
    for (int c = 1; c < 4; ++c) {
      float m2 = s_mn[c][tid]; int i2 = s_mi[c][tid];
      if (m2 < bm || (m2 == bm && i2 < best)) { bm = m2; best = i2; }
    }
    s_mi[0][tid] = best;                       // publish for gather below
    s_red[tid] = bm + s_x2[tid];               // SSE(row) = dist + |x|^2
    enc[(size_t)(row0 + tid) * K_CODES + best] = 1.0f;
    atomicAdd(&counts[best], 1);
  }
  __syncthreads();
  for (int m = 64; m > 0; m >>= 1) {
    if (tid < m) s_red[tid] += s_red[tid + m];
    __syncthreads();
  }
  if (tid == 0) ssep[abid] = s_red[0];

  // quantized gather: one wave per 16 rows, coalesced plain scalar stores
  // (dest is 4B-aligned only: quant = out+1).
  for (int r = ww * 16; r < ww * 16 + 16; ++r) {
    int best = s_mi[0][r];
    float4 v = ((const float4*)(cb + (size_t)best * D_DIM))[lane];
    float* qp = quant + (size_t)(row0 + r) * D_DIM + lane * 4;
    qp[0] = v.x; qp[1] = v.y; qp[2] = v.z; qp[3] = v.w;
  }
}

// ---------------------------------------------------------------------------
// Finalize: vq_loss + perplexity (deterministic fixed-order reductions).
// ---------------------------------------------------------------------------
__global__ __launch_bounds__(256) void finalize_kernel(
    const float* __restrict__ ssep, const int* __restrict__ counts,
    float* __restrict__ out) {
  __shared__ float r1[256], r2[256];
  int t = threadIdx.x;
  float s1 = ssep[t];  // 256 argmin blocks, one partial each
  float s2 = 0.f;
  for (int j = 0; j < 32; ++j) {
    float p = (float)counts[t * 32 + j] * (1.0f / 32768.f);
    s2 += p * logf(p + 1e-10f);
  }
  r1[t] = s1; r2[t] = s2;
  __syncthreads();
  for (int m = 128; m > 0; m >>= 1) {
    if (t < m) { r1[t] += r1[t + m]; r2[t] += r2[t + m]; }
    __syncthreads();
  }
  if (t == 0) {
    out[0] = 1.25f * r1[0] / 8388608.f;   // q_latent + 0.25*e_latent
    out[8388609] = expf(-r2[0]);          // perplexity
  }
}

extern "C" void kernel_launch(void* const* d_in, const int* in_sizes, int n_in,
                              void* d_out, int out_size, void* d_ws, size_t ws_size,
                              hipStream_t stream) {
  const float* x = (const float*)d_in[0];
  const float* cb = (const float*)d_in[1];
  float* out = (float*)d_out;
  char* w = (char*)d_ws;
  unsigned short* ehw = (unsigned short*)(w);           // 4.5 MiB swizzled bf16+c2
  int* counts = (int*)(w + 4718592);                    // 32 KiB
  float* ssep = (float*)(w + 4751360);                  // 1 KiB

  float* quant = out + 1;
  float* enc = out + 8388610;

  eprep_kernel<<<K_CODES / 4, 256, 0, stream>>>(cb, ehw, counts);
  argmin_kernel<<<256, 512, 0, stream>>>(x, cb, ehw, quant, counts, ssep, enc);
  finalize_kernel<<<1, 256, 0, stream>>>(ssep, counts, out);
}